// Round 8
// baseline (254.658 us; speedup 1.0000x reference)
//
#include <hip/hip_runtime.h>
#include <stdint.h>

// ---------------------------------------------------------------------------
// LatentMoE forward, MI355X (gfx950). TWO dispatches:
//  1. pack_kernel (wide): f32->bf16 convert + packing/transposes (+zero counts)
//  2. moe_mega (persistent, 256 blocks x 256 thr, relaxed-spin grid barriers):
//     P1 gemm1 -> P2 router -> P3 GU gemm(+SwiGLU) -> P4 down gemm
//     -> P5 combine(+z) -> P6 final gemm
// R8: GEMM = per-WAVE independent 64x64 tiles, private 24KB LDS slice/wave,
// depth-2 global_load_lds pipeline with counted vmcnt, NO s_barrier in K-loop
// (R7 showed barrier-lockstep at 1 wave/SIMD => ~4900cy/K-step, 552 GB/s).
// ---------------------------------------------------------------------------

using f32x4 = __attribute__((ext_vector_type(4))) float;
using s16x8 = __attribute__((ext_vector_type(8))) short;

#define MFMA_BF16(a, b, c) __builtin_amdgcn_mfma_f32_16x16x32_bf16((a), (b), (c), 0, 0, 0)

__device__ __forceinline__ unsigned short f2bf(float f) {
  union { float f; uint32_t u; } v; v.f = f;
  uint32_t u = v.u;
  u += 0x7FFFu + ((u >> 16) & 1u);
  return (unsigned short)(u >> 16);
}
__device__ __forceinline__ float bf2f(unsigned short h) {
  union { uint32_t u; float f; } v; v.u = ((uint32_t)h) << 16;
  return v.f;
}
__device__ __forceinline__ float silu_f(float x) { return x / (1.f + expf(-x)); }

__device__ __forceinline__ void cvt16(const float* __restrict__ src,
                                      unsigned short* __restrict__ dst) {
  if (src) {
#pragma unroll
    for (int i = 0; i < 4; ++i) {
      float4 v = *(const float4*)(src + i * 4);
      *(ushort4*)(dst + i * 4) =
          make_ushort4(f2bf(v.x), f2bf(v.y), f2bf(v.z), f2bf(v.w));
    }
  } else {
#pragma unroll
    for (int i = 0; i < 4; ++i) *(ushort4*)(dst + i * 4) = make_ushort4(0, 0, 0, 0);
  }
}

struct MegaArgs {
  const float *x, *gate, *down, *sgu, *sdw, *up, *egu, *edw, *bias;
  unsigned short *xb, *Wcat, *Bf, *egut, *edwt, *Abuf, *lat_g, *hide, *ybuf;
  float *C1, *lse2, *out;
  int *counts, *slot_nk;
  float *gw_nk;
  int *bars;
};

// ---------------------------------------------------------------------------
// Wide pack kernel (unchanged; ~16us, near its ~105MB/6.3TBps roofline)
// ---------------------------------------------------------------------------
__global__ void pack_kernel(MegaArgs a) {
  __shared__ float tile[32][33];
  const int b = blockIdx.x, t = threadIdx.x;
  if (b == 0 && t < 64) a.counts[t] = 0;
  if (b < 608) {
    const int r = b * 4 + (t >> 6), c = (t & 63) * 16;
    const float* src;
    if (r < 64)       src = a.gate + (size_t)r * 1024 + c;
    else if (r < 320) src = a.down + (size_t)(r - 64) * 1024 + c;
    else if (r < 384) src = nullptr;
    else {
      const int i = r - 384;
      src = a.sgu + (size_t)((i >> 1) + (i & 1) * 1024) * 1024 + c;
    }
    cvt16(src, a.Wcat + (size_t)r * 1024 + c);
  } else if (b < 928) {
    const int idx = (b - 608) * 4096 + t * 16;
    const int row = idx / 1280, col = idx - row * 1280;
    const float* src = (col < 1024) ? a.sdw + (size_t)row * 1024 + col
                                    : a.up + (size_t)row * 256 + (col - 1024);
    cvt16(src, a.Bf + idx);
  } else if (b < 1184) {
    const int idx = (b - 928) * 4096 + t * 16;
    cvt16(a.x + idx, a.xb + idx);
  } else {
    const float* src; unsigned short* dst; int lds, tr, tc; bool inter;
    if (b < 9376) {
      const int q = b - 1184, e = q >> 7, tt = q & 127;
      tr = tt >> 4; tc = tt & 15; lds = 512; inter = true;
      src = a.egu + (size_t)e * 131072; dst = a.egut + (size_t)e * 131072;
    } else {
      const int q = b - 9376, e = q >> 6, tt = q & 63;
      tr = tt >> 3; tc = tt & 7; lds = 256; inter = false;
      src = a.edw + (size_t)e * 65536; dst = a.edwt + (size_t)e * 65536;
    }
    const int r = t >> 3, c4 = (t & 7) * 4;
    float4 v = *(const float4*)(src + (size_t)(tr * 32 + r) * lds + tc * 32 + c4);
    tile[r][c4 + 0] = v.x; tile[r][c4 + 1] = v.y;
    tile[r][c4 + 2] = v.z; tile[r][c4 + 3] = v.w;
    __syncthreads();
    const int n = tc * 32 + r;
    const int orow = inter ? ((n < 256) ? 2 * n : 2 * (n - 256) + 1) : n;
    ushort4 o = make_ushort4(f2bf(tile[c4 + 0][r]), f2bf(tile[c4 + 1][r]),
                             f2bf(tile[c4 + 2][r]), f2bf(tile[c4 + 3][r]));
    *(ushort4*)(dst + (size_t)orow * 256 + tr * 32 + c4) = o;
  }
}

// ---------------------------------------------------------------------------
// Grid barrier: relaxed polls, one acquire fence on exit (R7-proven).
// ---------------------------------------------------------------------------
__device__ __forceinline__ void grid_barrier(int* bar, int nblk) {
  __syncthreads();
  if (threadIdx.x == 0) {
    __hip_atomic_fetch_add(bar, 1, __ATOMIC_RELEASE, __HIP_MEMORY_SCOPE_AGENT);
    while (__hip_atomic_load(bar, __ATOMIC_RELAXED, __HIP_MEMORY_SCOPE_AGENT) < nblk)
      __builtin_amdgcn_s_sleep(8);
    __builtin_amdgcn_fence(__ATOMIC_ACQUIRE, "agent");
  }
  __syncthreads();
}

// ---------------------------------------------------------------------------
// Per-wave GEMM: 64x64 output tile, BK=32, 3 LDS buffers (depth-2 prefetch),
// counted vmcnt, NO barriers. LDS slice layout per buffer: [kh=4][row=64][8e].
// ---------------------------------------------------------------------------
struct EpiArgs { int mode; void* out; int ldo; int coff; };

__device__ __forceinline__ void stage64(const unsigned short* __restrict__ G, int ldg,
                                        int row0, int kt, unsigned short* buf,
                                        int lane) {
#pragma unroll
  for (int j = 0; j < 4; ++j) {
    const unsigned short* src = G + (size_t)(row0 + lane) * ldg + kt * 32 + j * 8;
    __builtin_amdgcn_global_load_lds(
        (const __attribute__((address_space(1))) void*)src,
        (__attribute__((address_space(3))) void*)(buf + j * 512), 16, 0, 0);
  }
}

__device__ void wgemm(const unsigned short* __restrict__ A, int lda,
                      const unsigned short* __restrict__ B, int ldb,
                      int K, int m0, int n0, EpiArgs epi,
                      unsigned short* Ls) {
  const int lane = threadIdx.x & 63;
  const int kh = lane >> 4, r16 = lane & 15;
  unsigned short* As = Ls;             // 3 x 2048 ushorts
  unsigned short* Bs = Ls + 3 * 2048;  // 3 x 2048 ushorts

  f32x4 acc[4][4] = {};
  const int NT = K >> 5;

  stage64(A, lda, m0, 0, As, lane);
  stage64(B, ldb, n0, 0, Bs, lane);
  stage64(A, lda, m0, 1, As + 2048, lane);
  stage64(B, ldb, n0, 1, Bs + 2048, lane);

  int cur = 0;
  for (int kt = 0; kt < NT; ++kt) {
    const int rem = NT - 1 - kt;  // tiles still in flight beyond kt after stage
    if (rem >= 1) asm volatile("s_waitcnt vmcnt(8)" ::: "memory");
    else          asm volatile("s_waitcnt vmcnt(0)" ::: "memory");

    const unsigned short* Ab = As + cur * 2048;
    const unsigned short* Bb = Bs + cur * 2048;
    s16x8 af[4], bfr[4];
#pragma unroll
    for (int m = 0; m < 4; ++m)
      af[m] = *(const s16x8*)(Ab + kh * 512 + (m * 16 + r16) * 8);
#pragma unroll
    for (int n = 0; n < 4; ++n)
      bfr[n] = *(const s16x8*)(Bb + kh * 512 + (n * 16 + r16) * 8);

    if (kt + 2 < NT) {
      const int nb = (cur + 2 >= 3) ? cur - 1 : cur + 2;
      stage64(A, lda, m0, kt + 2, As + nb * 2048, lane);
      stage64(B, ldb, n0, kt + 2, Bs + nb * 2048, lane);
    }

#pragma unroll
    for (int m = 0; m < 4; ++m)
#pragma unroll
      for (int n = 0; n < 4; ++n)
        acc[m][n] = MFMA_BF16(af[m], bfr[n], acc[m][n]);

    cur = (cur + 1 == 3) ? 0 : cur + 1;
  }

  // epilogue: C/D layout col = lane&15, row = (lane>>4)*4 + reg
#pragma unroll
  for (int m = 0; m < 4; ++m) {
    const int rb = m0 + m * 16 + (lane >> 4) * 4;
#pragma unroll
    for (int n = 0; n < 4; ++n) {
      const int c = n0 + n * 16 + (lane & 15);
      if (epi.mode == 0) {
        float* O = (float*)epi.out;
#pragma unroll
        for (int j = 0; j < 4; ++j) O[(size_t)(rb + j) * epi.ldo + c] = acc[m][n][j];
      } else if (epi.mode == 1) {
        unsigned short* O = (unsigned short*)epi.out;
#pragma unroll
        for (int j = 0; j < 4; ++j)
          O[(size_t)(rb + j) * epi.ldo + c] = f2bf(acc[m][n][j]);
      } else {
        unsigned short* O = (unsigned short*)epi.out;
        const int col = (c - epi.coff) >> 1;
#pragma unroll
        for (int j = 0; j < 4; ++j) {
          const float v = acc[m][n][j];
          const float u = __shfl_xor(v, 1);
          if (!(lane & 1))
            O[(size_t)(rb + j) * epi.ldo + col] = f2bf(silu_f(v) * u);
        }
      }
    }
  }
}

// ---------------------------------------------------------------------------
// Router (one wave per token; 4 tokens per block)
// ---------------------------------------------------------------------------
__device__ void router_block(int b, int tid, const MegaArgs& a) {
  const int n = b * 4 + (tid >> 6);
  const int lane = tid & 63;
  const float* row = a.C1 + (size_t)n * 384;
  const float logit = row[lane];

  float mx = logit;
#pragma unroll
  for (int d = 32; d; d >>= 1) mx = fmaxf(mx, __shfl_xor(mx, d));
  float se = expf(logit - mx);
#pragma unroll
  for (int d = 32; d; d >>= 1) se += __shfl_xor(se, d);
  if (lane == 0) {
    const float lse = mx + logf(se);
    a.lse2[n] = lse * lse;
  }

  const float aff = 1.f / (1.f + expf(-logit));
  float s = aff + a.bias[lane];

  float asum = 0.f;
  int e_mine = 0; float a_mine = 0.f;
#pragma unroll
  for (int k = 0; k < 8; ++k) {
    float m2 = s;
#pragma unroll
    for (int d = 32; d; d >>= 1) m2 = fmaxf(m2, __shfl_xor(m2, d));
    const unsigned long long blt = __ballot(s == m2);
    const int idx = __ffsll(blt) - 1;
    const float af_ = __shfl(aff, idx);
    asum += af_;
    if (lane == k) { e_mine = idx; a_mine = af_; }
    if (lane == idx) s = -3.0e38f;
  }
  const float inv = 1.f / (asum + 1e-9f);

  int slot = 0;
  if (lane < 8) {
    int pos = atomicAdd(&a.counts[e_mine], 1);
    if (pos > 255) pos = 255;
    slot = e_mine * 256 + pos;
    a.slot_nk[(size_t)n * 8 + lane] = slot;
    a.gw_nk[(size_t)n * 8 + lane] = a_mine * inv;
  }

  const float4 lv = *(const float4*)(row + 64 + lane * 4);
  const ushort4 lb = make_ushort4(f2bf(lv.x), f2bf(lv.y), f2bf(lv.z), f2bf(lv.w));
#pragma unroll
  for (int k = 0; k < 8; ++k) {
    const int sl = __shfl(slot, k);
    *(ushort4*)(a.lat_g + (size_t)sl * 256 + lane * 4) = lb;
  }
}

// ---------------------------------------------------------------------------
// Combine (4 tokens per block) + z-loss reduce on block 0
// ---------------------------------------------------------------------------
__device__ void combine_block(int b, int tid, const MegaArgs& a, float* red) {
  const int n = b * 4 + (tid >> 6);
  const int l4 = (tid & 63) * 4;
  float a0 = 0.f, a1 = 0.f, a2 = 0.f, a3 = 0.f;
#pragma unroll
  for (int k = 0; k < 8; ++k) {
    const int sl = a.slot_nk[(size_t)n * 8 + k];
    const float g = a.gw_nk[(size_t)n * 8 + k];
    const ushort4 yv = *(const ushort4*)(a.ybuf + (size_t)sl * 256 + l4);
    a0 += g * bf2f(yv.x); a1 += g * bf2f(yv.y);
    a2 += g * bf2f(yv.z); a3 += g * bf2f(yv.w);
  }
  *(ushort4*)(a.Abuf + (size_t)n * 1280 + 1024 + l4) =
      make_ushort4(f2bf(a0), f2bf(a1), f2bf(a2), f2bf(a3));

  if (b == 0) {
    __syncthreads();
    float s = a.lse2[tid] + a.lse2[tid + 256] + a.lse2[tid + 512] + a.lse2[tid + 768];
    red[tid] = s;
    __syncthreads();
    for (int d = 128; d; d >>= 1) {
      if (tid < d) red[tid] += red[tid + d];
      __syncthreads();
    }
    if (tid == 0) a.out[1048576] = 0.001f * red[0] * (1.f / 1024.f);
  }
}

// ---------------------------------------------------------------------------
__global__ __launch_bounds__(256, 1) void moe_mega(MegaArgs a) {
  __shared__ __align__(16) unsigned short smw[4][12288];  // 24KB per wave
  const int b = blockIdx.x, tid = threadIdx.x;
  const int wid = tid >> 6;
  const int w = b * 4 + wid;           // global wave id [0,1024)
  unsigned short* Ls = smw[wid];

  // P1: gemm1, 16x38 tiles of 64x64 (608 wave-tiles)
  if (w < 608) {
    const int by = w / 38, bx = w % 38;
    EpiArgs e;
    if (bx < 6) { e.mode = 0; e.out = a.C1; e.ldo = 384; e.coff = 0; }
    else        { e.mode = 2; e.out = a.Abuf; e.ldo = 1280; e.coff = 384; }
    wgemm(a.xb, 1024, a.Wcat, 1024, 1024, by * 64, bx * 64, e, Ls);
  }
  grid_barrier(a.bars + 0, 256);

  // P2: router
  router_block(b, tid, a);
  grid_barrier(a.bars + 1, 256);

  // P3: grouped GU gemm + SwiGLU: 64 experts x 4 rowtiles x 8 coltiles = 2048
  for (int t = w; t < 2048; t += 1024) {
    const int e_ = t >> 5, rt = (t >> 3) & 3, ct = t & 7;
    int cnt = a.counts[e_];
    if (cnt > 256) cnt = 256;
    if (rt * 64 < cnt) {
      EpiArgs ep; ep.mode = 2; ep.out = a.hide; ep.ldo = 256; ep.coff = 0;
      wgemm(a.lat_g, 256, a.egut + (size_t)e_ * 131072, 256, 256,
            e_ * 256 + rt * 64, ct * 64, ep, Ls);
    }
  }
  grid_barrier(a.bars + 2, 256);

  // P4: grouped down gemm: 64 x 4 x 4 = 1024 wave-tiles
  {
    const int e_ = w >> 4, rt = (w >> 2) & 3, ct = w & 3;
    int cnt = a.counts[e_];
    if (cnt > 256) cnt = 256;
    if (rt * 64 < cnt) {
      EpiArgs ep; ep.mode = 1; ep.out = a.ybuf; ep.ldo = 256; ep.coff = 0;
      wgemm(a.hide, 256, a.edwt + (size_t)e_ * 65536, 256, 256,
            e_ * 256 + rt * 64, ct * 64, ep, Ls);
    }
  }
  grid_barrier(a.bars + 3, 256);

  // P5: combine + z reduce
  combine_block(b, tid, a, (float*)smw[0]);
  grid_barrier(a.bars + 4, 256);

  // P6: final gemm: 16x16 tiles of 64x64 = 256 wave-tiles
  if (w < 256) {
    EpiArgs e; e.mode = 0; e.out = a.out; e.ldo = 1024; e.coff = 0;
    wgemm(a.Abuf, 1280, a.Bf, 1280, 1280, (w >> 4) * 64, (w & 15) * 64, e, Ls);
  }
}

// ---------------------------------------------------------------------------
extern "C" void kernel_launch(void* const* d_in, const int* in_sizes, int n_in,
                              void* d_out, int out_size, void* d_ws, size_t ws_size,
                              hipStream_t stream) {
  (void)in_sizes; (void)n_in; (void)out_size; (void)ws_size;
  MegaArgs a;
  a.x    = (const float*)d_in[0];
  a.gate = (const float*)d_in[1];
  a.bias = (const float*)d_in[2];
  a.down = (const float*)d_in[3];
  a.up   = (const float*)d_in[4];
  a.sgu  = (const float*)d_in[5];
  a.sdw  = (const float*)d_in[6];
  a.egu  = (const float*)d_in[7];
  a.edw  = (const float*)d_in[8];
  a.out  = (float*)d_out;

  char* w = (char*)d_ws;
  auto alloc = [&](size_t bytes) { char* p = w; w += (bytes + 255) & ~(size_t)255; return p; };
  a.xb    = (unsigned short*)alloc(1048576ull * 2);
  a.Wcat  = (unsigned short*)alloc(2432ull * 1024 * 2);
  a.Bf    = (unsigned short*)alloc(1024ull * 1280 * 2);
  a.egut  = (unsigned short*)alloc(64ull * 512 * 256 * 2);
  a.edwt  = (unsigned short*)alloc(64ull * 256 * 256 * 2);
  a.C1    = (float*)alloc(1024ull * 384 * 4);
  a.Abuf  = (unsigned short*)alloc(1024ull * 1280 * 2);
  a.lat_g = (unsigned short*)alloc(16384ull * 256 * 2);
  a.hide  = (unsigned short*)alloc(16384ull * 256 * 2);
  a.ybuf  = (unsigned short*)alloc(16384ull * 256 * 2);
  a.lse2  = (float*)alloc(1024 * 4);
  a.counts  = (int*)alloc(64 * 4);
  a.slot_nk = (int*)alloc(8192 * 4);
  a.gw_nk   = (float*)alloc(8192 * 4);
  a.bars    = (int*)alloc(16 * 4);

  hipMemsetAsync(a.bars, 0, 16 * 4, stream);
  pack_kernel<<<dim3(13472), dim3(256), 0, stream>>>(a);
  moe_mega<<<dim3(256), dim3(256), 0, stream>>>(a);
}

// Round 9
// 126.612 us; speedup vs baseline: 2.0113x; 2.0113x over previous
//
#include <hip/hip_runtime.h>
#include <stdint.h>

// ---------------------------------------------------------------------------
// LatentMoE forward, MI355X (gfx950). 8 dispatches, all operands in a
// K-tile-contiguous layout (TIDX): each [128 rows x 32 cols] bf16 tile is a
// contiguous 8KB block, inner order [kh=4][row=128][8] = exactly the MFMA
// fragment order, so global_load_lds stages contiguous 1KB per instruction.
// GEMMs are 1-wave 64-thread blocks (64x64 tile, 16KB LDS, no barriers,
// counted vmcnt) -> up to 10 blocks/CU of TLP.
//  1 pack     : f32->bf16 + tiling + transposes (+zero counts, z slot)
//  2 wg1      : [logits|lat] f32 + fused shared SwiGLU -> Abuf (608 blocks)
//  3 router   : top-8, gates, z atomic, latent scatter (tiled)
//  4 wgGU     : grouped expert GU + SwiGLU (2048 blocks)
//  5 wgDW     : grouped expert down (1024 blocks)
//  6 combine  : top-8 weighted sum -> Abuf cols 1024..1279
//  7 wgF      : final GEMM, 4-way K-split -> 4 f32 partials (1024 blocks)
//  8 addF     : sum partials -> out
// ---------------------------------------------------------------------------

using f32x4 = __attribute__((ext_vector_type(4))) float;
using s16x8 = __attribute__((ext_vector_type(8))) short;

#define MFMA_BF16(a, b, c) __builtin_amdgcn_mfma_f32_16x16x32_bf16((a), (b), (c), 0, 0, 0)
#define AS1 __attribute__((address_space(1)))
#define AS3 __attribute__((address_space(3)))

__device__ __forceinline__ unsigned short f2bf(float f) {
  union { float f; uint32_t u; } v; v.f = f;
  uint32_t u = v.u;
  u += 0x7FFFu + ((u >> 16) & 1u);
  return (unsigned short)(u >> 16);
}
__device__ __forceinline__ float bf2f(unsigned short h) {
  union { uint32_t u; float f; } v; v.u = ((uint32_t)h) << 16;
  return v.f;
}
__device__ __forceinline__ float silu_f(float x) { return x / (1.f + expf(-x)); }

// tiled element address: [128-row x 32-col] tiles, inner [kh=4][row=128][8]
__device__ __forceinline__ size_t TIDX(int row, int col, int K) {
  return (((size_t)((row >> 7) * (K >> 5) + (col >> 5))) << 12) +
         (size_t)((((col >> 3) & 3) << 10) + ((row & 127) << 3) + (col & 7));
}

struct Args {
  const float *x, *gate, *down, *sgu, *sdw, *up, *egu, *edw, *bias;
  unsigned short *xb, *Wcat, *Bf, *egut, *edwt, *Abuf, *lat_g, *hide, *ybuf;
  float *C1, *Pf, *out;
  int *counts, *slot_nk;
  float *gw_nk;
};

// ---------------------------------------------------------------------------
// Pack: tile-blocks.  [0,608) Wcat 19x32 | [608,928) Bf 8x40 | [928,1184) xb
// 8x32 | [1184,9376) egut transpose | [9376,13472) edwt transpose
// ---------------------------------------------------------------------------
__global__ void pack_kernel(Args a) {
  __shared__ union { float lin[128 * 33]; float tp[32][33]; } sm;
  const int b = blockIdx.x, t = threadIdx.x;
  if (b == 0) {
    if (t < 64) a.counts[t] = 0;
    if (t == 64) a.out[1048576] = 0.f;
  }
  if (b < 1184) {
    // linear segments: load [128 x 32] f32 tile coalesced -> LDS -> tiled bf16
    int rt, kt, K;
    const float* base = nullptr;
    unsigned short* dst;
    if (b < 608)      { rt = b >> 5;          kt = b & 31; K = 1024; dst = a.Wcat; }
    else if (b < 928) { int q = b - 608; rt = q / 40; kt = q % 40; K = 1280; dst = a.Bf; }
    else              { int q = b - 928; rt = q >> 5; kt = q & 31; K = 1024; dst = a.xb; base = a.x; }

    const int r = t >> 1, half = t & 1;
    const int gr = rt * 128 + r;
    const int c0 = kt * 32 + half * 16;
    const float* s;
    if (b < 608) {
      if (gr < 64)       s = a.gate + (size_t)gr * 1024 + c0;
      else if (gr < 320) s = a.down + (size_t)(gr - 64) * 1024 + c0;
      else if (gr < 384) s = nullptr;
      else {
        const int i = gr - 384;
        s = a.sgu + (size_t)((i >> 1) + (i & 1) * 1024) * 1024 + c0;
      }
    } else if (b < 928) {
      s = (c0 < 1024) ? a.sdw + (size_t)gr * 1024 + c0
                      : a.up + (size_t)gr * 256 + (c0 - 1024);
    } else {
      s = base + (size_t)gr * 1024 + c0;
    }
#pragma unroll
    for (int i = 0; i < 4; ++i) {
      float4 v = s ? *(const float4*)(s + i * 4) : make_float4(0.f, 0.f, 0.f, 0.f);
      sm.lin[r * 33 + half * 16 + i * 4 + 0] = v.x;
      sm.lin[r * 33 + half * 16 + i * 4 + 1] = v.y;
      sm.lin[r * 33 + half * 16 + i * 4 + 2] = v.z;
      sm.lin[r * 33 + half * 16 + i * 4 + 3] = v.w;
    }
    __syncthreads();
    // write 16 consecutive tiled elems per thread (fully coalesced 8KB/block)
    const int j = t >> 6, r0 = (t & 63) * 2;
    unsigned short tmp[16];
#pragma unroll
    for (int rr = 0; rr < 2; ++rr)
#pragma unroll
      for (int c = 0; c < 8; ++c)
        tmp[rr * 8 + c] = f2bf(sm.lin[(r0 + rr) * 33 + j * 8 + c]);
    unsigned short* d = dst + ((size_t)(rt * (K >> 5) + kt) << 12) + t * 16;
    *(s16x8*)d = *(s16x8*)tmp;
    *(s16x8*)(d + 8) = *(s16x8*)(tmp + 8);
  } else {
    // transpose segments: 32x32 f32 tile through LDS -> tiled bf16 (TIDX)
    const float* src; unsigned short* dst; int lds, tr, tc; bool inter;
    if (b < 9376) {
      const int q = b - 1184, e = q >> 7, tt = q & 127;
      tr = tt >> 4; tc = tt & 15; lds = 512; inter = true;
      src = a.egu + (size_t)e * 131072; dst = a.egut + (size_t)e * 131072;
    } else {
      const int q = b - 9376, e = q >> 6, tt = q & 63;
      tr = tt >> 3; tc = tt & 7; lds = 256; inter = false;
      src = a.edw + (size_t)e * 65536; dst = a.edwt + (size_t)e * 65536;
    }
    const int r = t >> 3, c4 = (t & 7) * 4;
    float4 v = *(const float4*)(src + (size_t)(tr * 32 + r) * lds + tc * 32 + c4);
    sm.tp[r][c4 + 0] = v.x; sm.tp[r][c4 + 1] = v.y;
    sm.tp[r][c4 + 2] = v.z; sm.tp[r][c4 + 3] = v.w;
    __syncthreads();
    const int n = tc * 32 + r;
    const int orow = inter ? ((n < 256) ? 2 * n : 2 * (n - 256) + 1) : n;
    const int col = tr * 32 + c4;
    ushort4 o = make_ushort4(f2bf(sm.tp[c4 + 0][r]), f2bf(sm.tp[c4 + 1][r]),
                             f2bf(sm.tp[c4 + 2][r]), f2bf(sm.tp[c4 + 3][r]));
    *(ushort4*)(dst + TIDX(orow, col, 256)) = o;
  }
}

// ---------------------------------------------------------------------------
// 1-wave GEMM core: 64x64 tile, BK=32, 2 LDS buffers, counted vmcnt, no
// barriers. MODE: 0 = f32 linear store (ld = ldo), 1 = bf16 tiled store
// (ld = K of out buffer), 2 = SwiGLU pair -> bf16 tiled store.
// ---------------------------------------------------------------------------
template <int MODE>
__device__ void wgemm64(const unsigned short* __restrict__ A, int KA, int m0,
                        const unsigned short* __restrict__ B, int KB, int n0,
                        int kt0, int nkt, void* __restrict__ out, int ld, int coff,
                        unsigned short* __restrict__ L) {
  const int lane = threadIdx.x & 63;
  const unsigned short* Abase =
      A + (((size_t)((m0 >> 7) * (KA >> 5) + kt0)) << 12) + ((m0 >> 6) & 1) * 512;
  const unsigned short* Bbase =
      B + (((size_t)((n0 >> 7) * (KB >> 5) + kt0)) << 12) + ((n0 >> 6) & 1) * 512;
  unsigned short* As = L;
  unsigned short* Bs = L + 4096;

  auto stage = [&](int kt, int buf) {
    const unsigned short* at = Abase + ((size_t)kt << 12);
    const unsigned short* bt = Bbase + ((size_t)kt << 12);
#pragma unroll
    for (int j = 0; j < 4; ++j)
      __builtin_amdgcn_global_load_lds((const AS1 void*)(at + j * 1024 + lane * 8),
                                       (AS3 void*)(As + buf * 2048 + j * 512), 16, 0, 0);
#pragma unroll
    for (int j = 0; j < 4; ++j)
      __builtin_amdgcn_global_load_lds((const AS1 void*)(bt + j * 1024 + lane * 8),
                                       (AS3 void*)(Bs + buf * 2048 + j * 512), 16, 0, 0);
  };

  f32x4 acc[4][4] = {};
  stage(0, 0);
  const int kh = lane >> 4, r16 = lane & 15;
  for (int kt = 0; kt < nkt; ++kt) {
    if (kt + 1 < nkt) {
      stage(kt + 1, (kt + 1) & 1);
      asm volatile("s_waitcnt vmcnt(8)" ::: "memory");
    } else {
      asm volatile("s_waitcnt vmcnt(0)" ::: "memory");
    }
    const unsigned short* Ac = As + (kt & 1) * 2048;
    const unsigned short* Bc = Bs + (kt & 1) * 2048;
    s16x8 af[4], bfr[4];
#pragma unroll
    for (int m = 0; m < 4; ++m)
      af[m] = *(const s16x8*)(Ac + kh * 512 + (m * 16 + r16) * 8);
#pragma unroll
    for (int n = 0; n < 4; ++n)
      bfr[n] = *(const s16x8*)(Bc + kh * 512 + (n * 16 + r16) * 8);
#pragma unroll
    for (int m = 0; m < 4; ++m)
#pragma unroll
      for (int n = 0; n < 4; ++n)
        acc[m][n] = MFMA_BF16(af[m], bfr[n], acc[m][n]);
  }

  // epilogue: C/D layout col = lane&15, row = (lane>>4)*4 + reg
#pragma unroll
  for (int m = 0; m < 4; ++m) {
    const int rb = m0 + m * 16 + (lane >> 4) * 4;
#pragma unroll
    for (int n = 0; n < 4; ++n) {
      const int c = n0 + n * 16 + (lane & 15);
      if (MODE == 0) {
        float* O = (float*)out;
#pragma unroll
        for (int j = 0; j < 4; ++j) O[(size_t)(rb + j) * ld + c] = acc[m][n][j];
      } else if (MODE == 1) {
        unsigned short* O = (unsigned short*)out;
#pragma unroll
        for (int j = 0; j < 4; ++j) O[TIDX(rb + j, c, ld)] = f2bf(acc[m][n][j]);
      } else {
        unsigned short* O = (unsigned short*)out;
        const int col = (c - coff) >> 1;
#pragma unroll
        for (int j = 0; j < 4; ++j) {
          const float v = acc[m][n][j];
          const float u = __shfl_xor(v, 1);
          if (!(lane & 1)) O[TIDX(rb + j, col, ld)] = f2bf(silu_f(v) * u);
        }
      }
    }
  }
}

// wg1: 608 blocks = 16 mt x 38 nt. nt<6 -> C1 f32; else SwiGLU -> Abuf tiled.
__global__ __launch_bounds__(64, 3) void wg1(const unsigned short* __restrict__ xb,
                                             const unsigned short* __restrict__ Wcat,
                                             float* __restrict__ C1,
                                             unsigned short* __restrict__ Abuf) {
  __shared__ __align__(16) unsigned short L[8192];
  const int b = blockIdx.x, mt = b / 38, nt = b % 38;
  if (nt < 6)
    wgemm64<0>(xb, 1024, mt * 64, Wcat, 1024, nt * 64, 0, 32, C1, 384, 0, L);
  else
    wgemm64<2>(xb, 1024, mt * 64, Wcat, 1024, nt * 64, 0, 32, Abuf, 1280, 384, L);
}

// wgGU: 2048 blocks = e(64) x rt(4) x ct(8); SwiGLU -> hide tiled
__global__ __launch_bounds__(64, 3) void wgGU(const unsigned short* __restrict__ lat_g,
                                              const unsigned short* __restrict__ egut,
                                              unsigned short* __restrict__ hide,
                                              const int* __restrict__ counts) {
  __shared__ __align__(16) unsigned short L[8192];
  const int b = blockIdx.x, e = b >> 5, rt = (b >> 3) & 3, ct = b & 7;
  int cnt = counts[e];
  if (cnt > 256) cnt = 256;
  if (rt * 64 >= cnt) return;
  wgemm64<2>(lat_g, 256, e * 256 + rt * 64, egut + (size_t)e * 131072, 256,
             ct * 64, 0, 8, hide, 256, 0, L);
}

// wgDW: 1024 blocks = e(64) x rt(4) x ct(4); bf16 tiled -> ybuf
__global__ __launch_bounds__(64, 3) void wgDW(const unsigned short* __restrict__ hide,
                                              const unsigned short* __restrict__ edwt,
                                              unsigned short* __restrict__ ybuf,
                                              const int* __restrict__ counts) {
  __shared__ __align__(16) unsigned short L[8192];
  const int b = blockIdx.x, e = b >> 4, rt = (b >> 2) & 3, ct = b & 3;
  int cnt = counts[e];
  if (cnt > 256) cnt = 256;
  if (rt * 64 >= cnt) return;
  wgemm64<1>(hide, 256, e * 256 + rt * 64, edwt + (size_t)e * 65536, 256,
             ct * 64, 0, 8, ybuf, 256, 0, L);
}

// wgF: 1024 blocks = kc(4) x mt(16) x nt(16); f32 partials
__global__ __launch_bounds__(64, 3) void wgF(const unsigned short* __restrict__ Abuf,
                                             const unsigned short* __restrict__ Bf,
                                             float* __restrict__ Pf) {
  __shared__ __align__(16) unsigned short L[8192];
  const int b = blockIdx.x, kc = b >> 8, mt = (b >> 4) & 15, nt = b & 15;
  wgemm64<0>(Abuf, 1280, mt * 64, Bf, 1280, nt * 64, kc * 10, 10,
             Pf + (size_t)kc * 1048576, 1024, 0, L);
}

// addF: out = sum of 4 partials
__global__ void addF(const float* __restrict__ Pf, float* __restrict__ out) {
  const size_t i = (size_t)blockIdx.x * 1024 + threadIdx.x * 4;
  float4 s = *(const float4*)(Pf + i);
  const float4 b1 = *(const float4*)(Pf + 1048576 + i);
  const float4 b2 = *(const float4*)(Pf + 2097152 + i);
  const float4 b3 = *(const float4*)(Pf + 3145728 + i);
  s.x += b1.x + b2.x + b3.x; s.y += b1.y + b2.y + b3.y;
  s.z += b1.z + b2.z + b3.z; s.w += b1.w + b2.w + b3.w;
  *(float4*)(out + i) = s;
}

// ---------------------------------------------------------------------------
// Router: one wave per token (4 tokens/block). Writes lat_g TILED.
// ---------------------------------------------------------------------------
__global__ void router_kernel(Args a) {
  const int n = blockIdx.x * 4 + (threadIdx.x >> 6);
  const int lane = threadIdx.x & 63;
  const float* row = a.C1 + (size_t)n * 384;
  const float logit = row[lane];

  float mx = logit;
#pragma unroll
  for (int d = 32; d; d >>= 1) mx = fmaxf(mx, __shfl_xor(mx, d));
  float se = expf(logit - mx);
#pragma unroll
  for (int d = 32; d; d >>= 1) se += __shfl_xor(se, d);
  if (lane == 0) {
    const float lse = mx + logf(se);
    atomicAdd(a.out + 1048576, 0.001f * lse * lse * (1.f / 1024.f));
  }

  const float aff = 1.f / (1.f + expf(-logit));
  float s = aff + a.bias[lane];

  float asum = 0.f;
  int e_mine = 0; float a_mine = 0.f;
#pragma unroll
  for (int k = 0; k < 8; ++k) {
    float m2 = s;
#pragma unroll
    for (int d = 32; d; d >>= 1) m2 = fmaxf(m2, __shfl_xor(m2, d));
    const unsigned long long blt = __ballot(s == m2);
    const int idx = __ffsll(blt) - 1;  // lowest index on ties (matches top_k)
    const float af_ = __shfl(aff, idx);
    asum += af_;
    if (lane == k) { e_mine = idx; a_mine = af_; }
    if (lane == idx) s = -3.0e38f;
  }
  const float inv = 1.f / (asum + 1e-9f);

  int slot = 0;
  if (lane < 8) {
    int pos = atomicAdd(&a.counts[e_mine], 1);
    if (pos > 255) pos = 255;
    slot = e_mine * 256 + pos;
    a.slot_nk[(size_t)n * 8 + lane] = slot;
    a.gw_nk[(size_t)n * 8 + lane] = a_mine * inv;
  }

  const float4 lv = *(const float4*)(row + 64 + lane * 4);
  const ushort4 lb = make_ushort4(f2bf(lv.x), f2bf(lv.y), f2bf(lv.z), f2bf(lv.w));
#pragma unroll
  for (int k = 0; k < 8; ++k) {
    const int sl = __shfl(slot, k);
    *(ushort4*)(a.lat_g + TIDX(sl, lane * 4, 256)) = lb;
  }
}

// ---------------------------------------------------------------------------
// Combine: 4 tokens per block; reads ybuf tiled, writes Abuf cols 1024..1279.
// ---------------------------------------------------------------------------
__global__ void combine_kernel(Args a) {
  const int n = blockIdx.x * 4 + (threadIdx.x >> 6);
  const int l4 = (threadIdx.x & 63) * 4;
  float a0 = 0.f, a1 = 0.f, a2 = 0.f, a3 = 0.f;
#pragma unroll
  for (int k = 0; k < 8; ++k) {
    const int sl = a.slot_nk[(size_t)n * 8 + k];
    const float g = a.gw_nk[(size_t)n * 8 + k];
    const ushort4 yv = *(const ushort4*)(a.ybuf + TIDX(sl, l4, 256));
    a0 += g * bf2f(yv.x); a1 += g * bf2f(yv.y);
    a2 += g * bf2f(yv.z); a3 += g * bf2f(yv.w);
  }
  *(ushort4*)(a.Abuf + TIDX(n, 1024 + l4, 1280)) =
      make_ushort4(f2bf(a0), f2bf(a1), f2bf(a2), f2bf(a3));
}

// ---------------------------------------------------------------------------
extern "C" void kernel_launch(void* const* d_in, const int* in_sizes, int n_in,
                              void* d_out, int out_size, void* d_ws, size_t ws_size,
                              hipStream_t stream) {
  (void)in_sizes; (void)n_in; (void)out_size; (void)ws_size;
  Args a;
  a.x    = (const float*)d_in[0];
  a.gate = (const float*)d_in[1];
  a.bias = (const float*)d_in[2];
  a.down = (const float*)d_in[3];
  a.up   = (const float*)d_in[4];
  a.sgu  = (const float*)d_in[5];
  a.sdw  = (const float*)d_in[6];
  a.egu  = (const float*)d_in[7];
  a.edw  = (const float*)d_in[8];
  a.out  = (float*)d_out;

  char* w = (char*)d_ws;
  auto alloc = [&](size_t bytes) { char* p = w; w += (bytes + 255) & ~(size_t)255; return p; };
  a.xb    = (unsigned short*)alloc(1048576ull * 2);
  a.Wcat  = (unsigned short*)alloc(2432ull * 1024 * 2);
  a.Bf    = (unsigned short*)alloc(1024ull * 1280 * 2);
  a.egut  = (unsigned short*)alloc(64ull * 512 * 256 * 2);
  a.edwt  = (unsigned short*)alloc(64ull * 256 * 256 * 2);
  a.C1    = (float*)alloc(1024ull * 384 * 4);
  a.Abuf  = (unsigned short*)alloc(1024ull * 1280 * 2);
  a.lat_g = (unsigned short*)alloc(16384ull * 256 * 2);
  a.hide  = (unsigned short*)alloc(16384ull * 256 * 2);
  a.ybuf  = (unsigned short*)alloc(16384ull * 256 * 2);
  a.Pf    = (float*)alloc(4ull * 1048576 * 4);
  a.counts  = (int*)alloc(64 * 4);
  a.slot_nk = (int*)alloc(8192 * 4);
  a.gw_nk   = (float*)alloc(8192 * 4);

  pack_kernel<<<dim3(13472), dim3(256), 0, stream>>>(a);
  wg1<<<dim3(608), dim3(64), 0, stream>>>(a.xb, a.Wcat, a.C1, a.Abuf);
  router_kernel<<<dim3(256), dim3(256), 0, stream>>>(a);
  wgGU<<<dim3(2048), dim3(64), 0, stream>>>(a.lat_g, a.egut, a.hide, a.counts);
  wgDW<<<dim3(1024), dim3(64), 0, stream>>>(a.hide, a.edwt, a.ybuf, a.counts);
  combine_kernel<<<dim3(256), dim3(256), 0, stream>>>(a);
  wgF<<<dim3(1024), dim3(64), 0, stream>>>(a.Abuf, a.Bf, a.Pf);
  addF<<<dim3(1024), dim3(256), 0, stream>>>(a.Pf, a.out);
}